// Round 2
// baseline (232.636 us; speedup 1.0000x reference)
//
#include <hip/hip_runtime.h>

#define THREADS 256
#define GYRO_BLOCKS 256          // 65536 units, 1 unit (32 timesteps) per thread
#define GNLL_BLOCKS 1024
#define TOTAL_BLOCKS (GYRO_BLOCKS + GNLL_BLOCKS)

#define DT 0.005f
#define INV_HUBER 200.0f         // 1/0.005

#define NELEM 6291456            // 128*16384*3
#define N4 1572864               // NELEM/4
#define CNT16 391296.0           // 128*1019*3
#define CNT32 194688.0           // 128*507*3

// Rodrigues: R = I + st*W + ct*(phi phi^T - a2 I)
__device__ __forceinline__ void so3_exp3(float x, float y, float z, float R[9]) {
    float a2 = x * x + y * y + z * z;
    bool sm = a2 < 1e-12f;
    float a2s = sm ? 1.0f : a2;
    float a = sqrtf(a2s);
    float s = sinf(a);
    float c = cosf(a);
    float st = sm ? (1.0f - a2 * (1.0f / 6.0f)) : (s / a);
    float ct = sm ? (0.5f - a2 * (1.0f / 24.0f)) : ((1.0f - c) / a2s);
    R[0] = 1.0f + ct * (x * x - a2);
    R[1] = ct * (x * y) - st * z;
    R[2] = ct * (x * z) + st * y;
    R[3] = ct * (x * y) + st * z;
    R[4] = 1.0f + ct * (y * y - a2);
    R[5] = ct * (y * z) - st * x;
    R[6] = ct * (x * z) - st * y;
    R[7] = ct * (y * z) + st * x;
    R[8] = 1.0f + ct * (z * z - a2);
}

__device__ __forceinline__ void mm3(const float A[9], const float B[9], float C[9]) {
#pragma unroll
    for (int i = 0; i < 3; ++i) {
        float a0 = A[3 * i], a1 = A[3 * i + 1], a2 = A[3 * i + 2];
        C[3 * i + 0] = a0 * B[0] + a1 * B[3] + a2 * B[6];
        C[3 * i + 1] = a0 * B[1] + a1 * B[4] + a2 * B[7];
        C[3 * i + 2] = a0 * B[2] + a1 * B[5] + a2 * B[8];
    }
}

// sum of huber( so3_log(A^T B) / HUBER ) over the 3 components
__device__ __forceinline__ float huber_bmtm(const float A[9], const float B[9]) {
    float tr = 0.f, w0 = 0.f, w1 = 0.f, w2 = 0.f;
#pragma unroll
    for (int k = 0; k < 3; ++k) {
        float a0 = A[3 * k], a1 = A[3 * k + 1], a2v = A[3 * k + 2];
        float b0 = B[3 * k], b1 = B[3 * k + 1], b2v = B[3 * k + 2];
        tr += a0 * b0 + a1 * b1 + a2v * b2v;   // trace(A^T B)
        w0 += a2v * b1 - a1 * b2v;             // M[2][1]-M[1][2]
        w1 += a0 * b2v - a2v * b0;             // M[0][2]-M[2][0]
        w2 += a1 * b0 - a0 * b1;               // M[1][0]-M[0][1]
    }
    float cs = 0.5f * (tr - 1.0f);
    cs = fminf(fmaxf(cs, -1.0f + 1e-6f), 1.0f - 1e-6f);
    float ang = acosf(cs);
    float fac = ang / (2.0f * sinf(ang));      // clamp => ang >= ~1.4e-3, no small branch
    float h = 0.0f, r;
    r = fabsf(fac * w0 * INV_HUBER); h += (r < 1.0f) ? 0.5f * r * r : (r - 0.5f);
    r = fabsf(fac * w1 * INV_HUBER); h += (r < 1.0f) ? 0.5f * r * r : (r - 0.5f);
    r = fabsf(fac * w2 * INV_HUBER); h += (r < 1.0f) ? 0.5f * r * r : (r - 0.5f);
    return h;
}

__global__ __launch_bounds__(THREADS) void dg_loss_kernel(
    const float* __restrict__ w_hat, const float* __restrict__ dw16,
    const float* __restrict__ w_gt, const float* __restrict__ w_mean,
    const float* __restrict__ w_std, float* __restrict__ out,
    double* acc, unsigned int* counter)
{
    double lg = 0.0, lh16 = 0.0, lh32 = 0.0;
    const int bx = blockIdx.x;

    if (bx < GYRO_BLOCKS) {
        // ---- gyro: one 32-timestep unit per thread ----
        const int u = bx * THREADS + threadIdx.x;          // 0..65535
        const float* wp = w_hat + (size_t)u * 96;          // 32 rows * 3, 16B aligned
        float buf[48];
        float Pa[9], Pb[9], R[9], T[9];

        // chain A: product of exp(DT*w_hat[rows 0..15])
#pragma unroll
        for (int q = 0; q < 12; ++q) {
            float4 v = reinterpret_cast<const float4*>(wp)[q];
            buf[4 * q] = v.x; buf[4 * q + 1] = v.y; buf[4 * q + 2] = v.z; buf[4 * q + 3] = v.w;
        }
        so3_exp3(DT * buf[0], DT * buf[1], DT * buf[2], Pa);
#pragma unroll
        for (int j = 1; j < 16; ++j) {
            so3_exp3(DT * buf[3 * j], DT * buf[3 * j + 1], DT * buf[3 * j + 2], R);
            mm3(Pa, R, T);
#pragma unroll
            for (int e = 0; e < 9; ++e) Pa[e] = T[e];
        }
        // chain B: rows 16..31
#pragma unroll
        for (int q = 0; q < 12; ++q) {
            float4 v = reinterpret_cast<const float4*>(wp + 48)[q];
            buf[4 * q] = v.x; buf[4 * q + 1] = v.y; buf[4 * q + 2] = v.z; buf[4 * q + 3] = v.w;
        }
        so3_exp3(DT * buf[0], DT * buf[1], DT * buf[2], Pb);
#pragma unroll
        for (int j = 1; j < 16; ++j) {
            so3_exp3(DT * buf[3 * j], DT * buf[3 * j + 1], DT * buf[3 * j + 2], R);
            mm3(Pb, R, T);
#pragma unroll
            for (int e = 0; e < 9; ++e) Pb[e] = T[e];
        }

        // Q16 pair: exp(dw16[row 32u]) and exp(dw16[row 32u+16])  (rows 16g of flat array)
        float4 qa4 = *reinterpret_cast<const float4*>(dw16 + (size_t)u * 96);
        float4 qb4 = *reinterpret_cast<const float4*>(dw16 + (size_t)u * 96 + 48);
        float Qa[9], Qb[9];
        so3_exp3(qa4.x, qa4.y, qa4.z, Qa);
        so3_exp3(qb4.x, qb4.y, qb4.z, Qb);

        const int i2 = u & 511;                 // 32-block index within trajectory
        if (i2 >= 3) lh16 += huber_bmtm(Pa, Qa);   // 16-block 2*i2   >= 5
        if (i2 >= 2) lh16 += huber_bmtm(Pb, Qb);   // 16-block 2*i2+1 >= 5
        if (i2 >= 5) {
            float P32[9], Q32[9];
            mm3(Pa, Pb, P32);
            mm3(Qa, Qb, Q32);
            lh32 += huber_bmtm(P32, Q32);
        }
    } else {
        // ---- gaussian NLL: grid-stride over float4 ----
        const int t = (bx - GYRO_BLOCKS) * THREADS + threadIdx.x;
        const float4* h4 = reinterpret_cast<const float4*>(w_hat);
        const float4* g4 = reinterpret_cast<const float4*>(w_gt);
        const float4* m4 = reinterpret_cast<const float4*>(w_mean);
        const float4* s4 = reinterpret_cast<const float4*>(w_std);
        for (int i = t; i < N4; i += GNLL_BLOCKS * THREADS) {   // exactly 6 iters/thread
            float4 hh = h4[i], gg = g4[i], mv = m4[i], sv = s4[i];
            float p = 0.f;
            {
                float var = fmaxf(sv.x * sv.x, 1e-6f);
                float d = gg.x - hh.x - mv.x;
                p += logf(var) + d * d / var;
            }
            {
                float var = fmaxf(sv.y * sv.y, 1e-6f);
                float d = gg.y - hh.y - mv.y;
                p += logf(var) + d * d / var;
            }
            {
                float var = fmaxf(sv.z * sv.z, 1e-6f);
                float d = gg.z - hh.z - mv.z;
                p += logf(var) + d * d / var;
            }
            {
                float var = fmaxf(sv.w * sv.w, 1e-6f);
                float d = gg.w - hh.w - mv.w;
                p += logf(var) + d * d / var;
            }
            lg += 0.5 * (double)p;
        }
    }

    // ---- block reduction (3 doubles) ----
    __shared__ double s_g[4], s_h16[4], s_h32[4];
#pragma unroll
    for (int off = 32; off > 0; off >>= 1) {
        lg += __shfl_down(lg, off);
        lh16 += __shfl_down(lh16, off);
        lh32 += __shfl_down(lh32, off);
    }
    const int lane = threadIdx.x & 63, wv = threadIdx.x >> 6;
    if (lane == 0) { s_g[wv] = lg; s_h16[wv] = lh16; s_h32[wv] = lh32; }
    __syncthreads();
    if (threadIdx.x == 0) {
        double g = s_g[0] + s_g[1] + s_g[2] + s_g[3];
        double h16 = s_h16[0] + s_h16[1] + s_h16[2] + s_h16[3];
        double h32 = s_h32[0] + s_h32[1] + s_h32[2] + s_h32[3];
        atomicAdd(&acc[0], g);
        atomicAdd(&acc[1], h16);
        atomicAdd(&acc[2], h32);
        __threadfence();
        unsigned prev = atomicAdd(counter, 1u);
        if (prev == TOTAL_BLOCKS - 1) {
            // atomic reads to cross XCD L2s safely
            double ga = atomicAdd(&acc[0], 0.0);
            double h16a = atomicAdd(&acc[1], 0.0);
            double h32a = atomicAdd(&acc[2], 0.0);
            // gyro16 = W*HUBER^2*mean = 25*mean16 ; gyro32 = 25*mean32/4 ; gnll = mean
            out[0] = (float)(25.0 * (h16a / CNT16) + 6.25 * (h32a / CNT32) + ga / (double)NELEM);
        }
    }
}

extern "C" void kernel_launch(void* const* d_in, const int* in_sizes, int n_in,
                              void* d_out, int out_size, void* d_ws, size_t ws_size,
                              hipStream_t stream) {
    const float* w_hat = (const float*)d_in[0];
    const float* dw16 = (const float*)d_in[1];
    const float* w_gt = (const float*)d_in[2];
    const float* w_mean = (const float*)d_in[3];
    const float* w_std = (const float*)d_in[4];
    float* out = (float*)d_out;

    double* acc = (double*)d_ws;                       // acc[0..2]
    unsigned int* counter = (unsigned int*)((char*)d_ws + 24);

    hipMemsetAsync(d_ws, 0, 32, stream);               // zero accumulators + counter
    dg_loss_kernel<<<TOTAL_BLOCKS, THREADS, 0, stream>>>(
        w_hat, dw16, w_gt, w_mean, w_std, out, acc, counter);
}